// Round 4
// baseline (8552.637 us; speedup 1.0000x reference)
//
#include <hip/hip_runtime.h>
#include <hip/hip_bf16.h>

#define NPTS 8192
#define KNN  20
#define KC   4

__device__ __forceinline__ unsigned fkey(float f) {
  unsigned u = __float_as_uint(f);
  return (u & 0x80000000u) ? ~u : (u | 0x80000000u);
}
__device__ __forceinline__ float funkey(unsigned k) {
  return (k & 0x80000000u) ? __uint_as_float(k & 0x7fffffffu) : __uint_as_float(~k);
}
__device__ __forceinline__ float lrelu(float x) { return x >= 0.f ? x : 0.2f * x; }

// ---------------------------------------------------------------- prep weights
// Conv weights transposed as float4 [ci4][64] (lane-consecutive); w1a folded
// for the duplicated-xyz input; wg transposed to [c][o].
__global__ __launch_bounds__(256) void prep_kernel(
    const float* __restrict__ w1a, const float* __restrict__ w1b,
    const float* __restrict__ w2a, const float* __restrict__ w2b,
    const float* __restrict__ w3a, const float* __restrict__ wg,
    float* __restrict__ wp1A, float* __restrict__ wp1B,
    float* __restrict__ wp2A, float* __restrict__ wp2B,
    float* __restrict__ wp3A, float* __restrict__ wgT)
{
  const int t0 = blockIdx.x * blockDim.x + threadIdx.x;
  const int NT = gridDim.x * blockDim.x;
  for (int f = t0; f < 512; f += NT) {            // wp1A [2][64] f4, folded
    int i = f & 3, o = (f >> 2) & 63, c4 = f >> 8, c = c4 * 4 + i;
    float v = 0.f;
    if (c < 3)      v = w1a[o*12 + c]     + w1a[o*12 + c + 3];
    else if (c < 6) v = w1a[o*12 + c + 3] + w1a[o*12 + c + 6];
    wp1A[f] = v;
  }
  for (int f = t0; f < 4096; f += NT) {           // wp1B / wp2B [16][64] f4
    int i = f & 3, o = (f >> 2) & 63, c4 = f >> 8, c = c4 * 4 + i;
    wp1B[f] = w1b[o*64 + c];
    wp2B[f] = w2b[o*64 + c];
  }
  for (int f = t0; f < 8192; f += NT) {           // wp2A / wp3A [32][64] f4
    int i = f & 3, o = (f >> 2) & 63, c4 = f >> 8, c = c4 * 4 + i;
    wp2A[f] = w2a[o*128 + c];
    wp3A[f] = w3a[o*128 + c];
  }
  for (int f = t0; f < 192 * 1024; f += NT) {     // wgT [192][1024]
    int c = f >> 10, o = f & 1023;
    wgT[f] = wg[o*192 + c];
  }
}

// ---------------------------------------------------------------- point norms
__global__ __launch_bounds__(256) void xx_points(const float* __restrict__ pts,
                                                 float* __restrict__ xx)
{
  int t = blockIdx.x * 256 + threadIdx.x;
  if (t < 2 * NPTS) {
    const float* p = pts + (size_t)t * 3;
    xx[t] = p[0]*p[0] + p[1]*p[1] + p[2]*p[2];
  }
}

// ---------------------------------------------------------------- kNN
// ONE row per block, 256 threads, 32KB LDS. Distances to all 8192 points in
// LDS; then 20 rounds of barrier-synced block argmax (per-thread scan of 32
// strided elems -> wave shuffle reduce -> 4-entry LDS merge -> mark -INF).
// Tie-break: lower index wins (matches lax.top_k). Every LDS dependency
// crosses a __syncthreads().
template<int D>
__global__ __launch_bounds__(256) void knn_kernel(
    const float* __restrict__ feat, int fstride, int foff,
    const float* __restrict__ xx, int* __restrict__ idxout)
{
  __shared__ __align__(16) float sd[NPTS];          // 32 KB
  __shared__ __align__(16) float s_ctr[(D + 3) & ~3];
  __shared__ float s_bv[4];
  __shared__ int   s_bj[4];
  const int tid = threadIdx.x;
  const int b   = blockIdx.x >> 13;
  const int row = blockIdx.x & (NPTS - 1);
  const size_t rowbase = (size_t)b * NPTS;

  if (tid < D) s_ctr[tid] = feat[(rowbase + row) * fstride + foff + tid];
  __syncthreads();
  const float xr = xx[rowbase + row];

  for (int j = tid; j < NPTS; j += 256) {
    const float* fj = feat + (rowbase + j) * fstride + foff;
    float inner;
    if (D == 64) {
      const float4* fj4 = (const float4*)fj;
      const float4* cp  = (const float4*)s_ctr;
      inner = 0.f;
      #pragma unroll
      for (int c4 = 0; c4 < 16; ++c4) {
        float4 f = fj4[c4], a = cp[c4];
        inner += f.x*a.x + f.y*a.y + f.z*a.z + f.w*a.w;
      }
    } else {
      inner = fj[0]*s_ctr[0] + fj[1]*s_ctr[1] + fj[2]*s_ctr[2];
    }
    sd[j] = 2.f*inner - xr - xx[rowbase + j];
  }
  __syncthreads();

  int* orow = idxout + (rowbase + row) * KNN;
  const int lane = tid & 63, wv = tid >> 6;
  for (int kk = 0; kk < KNN; ++kk) {
    float bv = -INFINITY; int bj = NPTS;
    #pragma unroll
    for (int i = 0; i < NPTS / 256; ++i) {
      int j = i * 256 + tid;                 // ascending j: strict > keeps lowest
      float v = sd[j];
      if (v > bv) { bv = v; bj = j; }
    }
    #pragma unroll
    for (int m = 32; m >= 1; m >>= 1) {
      float ov = __shfl_xor(bv, m); int oj = __shfl_xor(bj, m);
      if (ov > bv || (ov == bv && oj < bj)) { bv = ov; bj = oj; }
    }
    if (lane == 0) { s_bv[wv] = bv; s_bj[wv] = bj; }
    __syncthreads();
    float fv = s_bv[0]; int fj2 = s_bj[0];
    #pragma unroll
    for (int w = 1; w < 4; ++w) {
      float ov = s_bv[w]; int oj = s_bj[w];
      if (ov > fv || (ov == fv && oj < fj2)) { fv = ov; fj2 = oj; }
    }
    if (tid == 0) { orow[kk] = fj2; sd[fj2] = -INFINITY; }
    __syncthreads();
  }
}

// ---------------------------------------------------------------- fused EdgeConv
// Block = 4 points x 64 channels (wave = one point). All LDS <= 64KB (KC=4).
template<int D, bool HASB, bool WXX>
__global__ __launch_bounds__(256) void fused_conv(
    const float* __restrict__ feat, int fstride, int foff,
    const int* __restrict__ idx,
    const float4* __restrict__ wAp, const float* __restrict__ sa, const float* __restrict__ ba,
    const float4* __restrict__ wBp, const float* __restrict__ sb, const float* __restrict__ bb,
    float* __restrict__ outbuf, int ooff, float* __restrict__ xxout)
{
  constexpr int CHA  = (D == 64) ? 32 : 2;   // float4 chunks of 2D (padded)
  constexpr int CHA4 = CHA * 4;
  __shared__ float4 s_wA[CHA * 64];                       // 32KB / 2KB
  __shared__ float4 s_wB[HASB ? 16 * 64 : 1];             // 16KB
  __shared__ __align__(16) float4 s_g[4 * KC * CHA];      // 8KB / 512B
  __shared__ __align__(16) float  s_h1[HASB ? 4 * KC * 64 : 4];  // 4KB
  __shared__ float s_ctr[4][(D > 4) ? D : 4];
  __shared__ float s_sa[64], s_ba[64], s_sb[64], s_bb[64];

  const int tid = threadIdx.x;
  const int p = tid >> 6, o = tid & 63;
  const int b  = blockIdx.x / (NPTS / 4);
  const int p0 = (blockIdx.x % (NPTS / 4)) * 4;
  const size_t rowbase = (size_t)b * NPTS;

  for (int i = tid; i < CHA * 64; i += 256) s_wA[i] = wAp[i];
  if (HASB) for (int i = tid; i < 16 * 64; i += 256) s_wB[i] = wBp[i];
  if (tid < 64) {
    s_sa[tid] = sa[tid]; s_ba[tid] = ba[tid];
    if (HASB) { s_sb[tid] = sb[tid]; s_bb[tid] = bb[tid]; }
  }
  for (int i = tid; i < 4 * D; i += 256)
    s_ctr[i / D][i % D] = feat[(rowbase + p0 + (i / D)) * fstride + foff + (i % D)];
  __syncthreads();

  float* s_gf = (float*)s_g;
  float hmax = -INFINITY;
  for (int kc = 0; kc < KNN / KC; ++kc) {
    for (int s = tid; s < 4 * KC * CHA4; s += 256) {
      int pp = s / (KC * CHA4);
      int rr = s - pp * (KC * CHA4);
      int kk = rr / CHA4;
      int c  = rr - kk * CHA4;
      int nb = idx[(rowbase + p0 + pp) * KNN + kc * KC + kk];
      float v;
      if (D == 64) {
        v = (c < 64) ? (feat[(rowbase + nb) * fstride + foff + c] - s_ctr[pp][c])
                     : s_ctr[pp][c - 64];
      } else {
        if (c < 3)      v = feat[(rowbase + nb) * 3 + c] - s_ctr[pp][c];
        else if (c < 6) v = s_ctr[pp][c - 3];
        else            v = 0.f;
      }
      s_gf[s] = v;
    }
    __syncthreads();

    float acc[KC];
    #pragma unroll
    for (int kk = 0; kk < KC; ++kk) acc[kk] = 0.f;
    for (int c4 = 0; c4 < CHA; ++c4) {
      float4 w = s_wA[c4 * 64 + o];
      #pragma unroll
      for (int kk = 0; kk < KC; ++kk) {
        float4 g = s_g[(p * KC + kk) * CHA + c4];
        acc[kk] += w.x*g.x + w.y*g.y + w.z*g.z + w.w*g.w;
      }
    }
    if (HASB) {
      #pragma unroll
      for (int kk = 0; kk < KC; ++kk)
        s_h1[(p * KC + kk) * 64 + o] = lrelu(acc[kk] * s_sa[o] + s_ba[o]);
      __syncthreads();
      float acc2[KC];
      #pragma unroll
      for (int kk = 0; kk < KC; ++kk) acc2[kk] = 0.f;
      const float4* s_h14 = (const float4*)s_h1;
      for (int c4 = 0; c4 < 16; ++c4) {
        float4 w = s_wB[c4 * 64 + o];
        #pragma unroll
        for (int kk = 0; kk < KC; ++kk) {
          float4 h = s_h14[(p * KC + kk) * 16 + c4];
          acc2[kk] += w.x*h.x + w.y*h.y + w.z*h.z + w.w*h.w;
        }
      }
      #pragma unroll
      for (int kk = 0; kk < KC; ++kk)
        hmax = fmaxf(hmax, lrelu(acc2[kk] * s_sb[o] + s_bb[o]));
      __syncthreads();
    } else {
      #pragma unroll
      for (int kk = 0; kk < KC; ++kk)
        hmax = fmaxf(hmax, lrelu(acc[kk] * s_sa[o] + s_ba[o]));
      __syncthreads();
    }
  }
  outbuf[(rowbase + p0 + p) * 192 + ooff + o] = hmax;
  if (WXX) {
    float ss = hmax * hmax;
    #pragma unroll
    for (int m = 1; m < 64; m <<= 1) ss += __shfl_xor(ss, m);
    if (o == 0) xxout[rowbase + p0 + p] = ss;
  }
}

// ---------------------------------------------------------------- final 192->1024
__global__ __launch_bounds__(256) void init_gmax(unsigned* __restrict__ g)
{
  int t = blockIdx.x * 256 + threadIdx.x;
  if (t < 2048) g[t] = fkey(-1e30f);   // sentinel: screams if final never runs
}

__global__ __launch_bounds__(256) void final_kernel(
    const float* __restrict__ cat, const float* __restrict__ wgT,
    const float* __restrict__ sg, const float* __restrict__ bg,
    unsigned* __restrict__ gmax)
{
  const int tid = threadIdx.x;
  const int chunk = blockIdx.x & 15;   // 16 chunks of 64 channels
  const int grp   = blockIdx.x >> 4;   // 64 groups of 256 points
  const int pt = grp * 256 + tid;      // flat over B*N
  const int b  = pt >> 13;
  const float4* crow = (const float4*)(cat + (size_t)pt * 192);
  float acc[64];
  #pragma unroll
  for (int o = 0; o < 64; ++o) acc[o] = 0.f;
  for (int c4 = 0; c4 < 48; ++c4) {
    float4 cv = crow[c4];
    const float* w0 = wgT + (size_t)(c4 * 4) * 1024 + chunk * 64;
    const float* w1 = w0 + 1024;
    const float* w2 = w1 + 1024;
    const float* w3 = w2 + 1024;
    #pragma unroll
    for (int o = 0; o < 64; ++o)
      acc[o] += cv.x*w0[o] + cv.y*w1[o] + cv.z*w2[o] + cv.w*w3[o];
  }
  const int lane = tid & 63;
  #pragma unroll
  for (int o = 0; o < 64; ++o) {
    int ch = chunk * 64 + o;
    float h = lrelu(acc[o] * sg[ch] + bg[ch]);
    #pragma unroll
    for (int m = 1; m < 64; m <<= 1) h = fmaxf(h, __shfl_xor(h, m));
    if (lane == 0) atomicMax(&gmax[b * 1024 + ch], fkey(h));
  }
}

// Output is FP32 (reference is pure float32): [2][1024][8192] floats.
__global__ __launch_bounds__(256) void bcast_kernel(const unsigned* __restrict__ gmax,
                                                    float* __restrict__ out)
{
  int t = blockIdx.x * 256 + threadIdx.x;   // each thread: 4 floats = 16B
  int bo = t >> 11;                          // (t*4) >> 13
  float v = funkey(gmax[bo]);
  float4 w; w.x = v; w.y = v; w.z = v; w.w = v;
  ((float4*)out)[t] = w;
}

// ---------------------------------------------------------------- launch
extern "C" void kernel_launch(void* const* d_in, const int* in_sizes, int n_in,
                              void* d_out, int out_size, void* d_ws, size_t ws_size,
                              hipStream_t stream)
{
  const float* points = (const float*)d_in[0];
  const float* w1a = (const float*)d_in[1];  const float* s1a = (const float*)d_in[2];  const float* b1a = (const float*)d_in[3];
  const float* w1b = (const float*)d_in[4];  const float* s1b = (const float*)d_in[5];  const float* b1b = (const float*)d_in[6];
  const float* w2a = (const float*)d_in[7];  const float* s2a = (const float*)d_in[8];  const float* b2a = (const float*)d_in[9];
  const float* w2b = (const float*)d_in[10]; const float* s2b = (const float*)d_in[11]; const float* b2b = (const float*)d_in[12];
  const float* w3a = (const float*)d_in[13]; const float* s3a = (const float*)d_in[14]; const float* b3a = (const float*)d_in[15];
  const float* wg  = (const float*)d_in[16]; const float* sg  = (const float*)d_in[17]; const float* bg  = (const float*)d_in[18];

  char* ws = (char*)d_ws;
  float*    cat   = (float*)(ws);                   // [2*8192][192]  12,582,912 B
  float*    xxbuf = (float*)(ws + 12582912);        // [2*8192]           65,536 B
  int*      idxb  = (int*)  (ws + 12648448);        // [2*8192][20]    1,310,720 B
  float*    wp1A  = (float*)(ws + 13959168);        //     2,048 B
  float*    wp1B  = (float*)(ws + 13961216);        //    16,384 B
  float*    wp2A  = (float*)(ws + 13977600);        //    32,768 B
  float*    wp2B  = (float*)(ws + 14010368);        //    16,384 B
  float*    wp3A  = (float*)(ws + 14026752);        //    32,768 B
  float*    wgT   = (float*)(ws + 14059520);        //   786,432 B
  unsigned* gmax  = (unsigned*)(ws + 14845952);     //     8,192 B
  const size_t WS_NEED = 14854144;
  if (ws_size < WS_NEED || n_in != 19) return;      // untouched-output signature

  prep_kernel<<<256, 256, 0, stream>>>(w1a, w1b, w2a, w2b, w3a, wg,
                                       wp1A, wp1B, wp2A, wp2B, wp3A, wgT);
  xx_points<<<64, 256, 0, stream>>>(points, xxbuf);
  knn_kernel<3><<<16384, 256, 0, stream>>>(points, 3, 0, xxbuf, idxb);
  fused_conv<3, true, true><<<4096, 256, 0, stream>>>(
      points, 3, 0, idxb, (const float4*)wp1A, s1a, b1a,
      (const float4*)wp1B, s1b, b1b, cat, 0, xxbuf);
  knn_kernel<64><<<16384, 256, 0, stream>>>(cat, 192, 0, xxbuf, idxb);
  fused_conv<64, true, true><<<4096, 256, 0, stream>>>(
      cat, 192, 0, idxb, (const float4*)wp2A, s2a, b2a,
      (const float4*)wp2B, s2b, b2b, cat, 64, xxbuf);
  knn_kernel<64><<<16384, 256, 0, stream>>>(cat, 192, 64, xxbuf, idxb);
  fused_conv<64, false, false><<<4096, 256, 0, stream>>>(
      cat, 192, 64, idxb, (const float4*)wp3A, s3a, b3a,
      nullptr, nullptr, nullptr, cat, 128, nullptr);
  init_gmax<<<8, 256, 0, stream>>>(gmax);
  final_kernel<<<1024, 256, 0, stream>>>(cat, wgT, sg, bg, gmax);
  bcast_kernel<<<16384, 256, 0, stream>>>(gmax, (float*)d_out);
}

// Round 5
// 6252.964 us; speedup vs baseline: 1.3678x; 1.3678x over previous
//
#include <hip/hip_runtime.h>
#include <hip/hip_bf16.h>

#define NPTS 8192
#define KNN  20
#define KC   4

__device__ __forceinline__ unsigned fkey(float f) {
  unsigned u = __float_as_uint(f);
  return (u & 0x80000000u) ? ~u : (u | 0x80000000u);
}
__device__ __forceinline__ float funkey(unsigned k) {
  return (k & 0x80000000u) ? __uint_as_float(k & 0x7fffffffu) : __uint_as_float(~k);
}
__device__ __forceinline__ float lrelu(float x) { return x >= 0.f ? x : 0.2f * x; }

// ---------------------------------------------------------------- prep weights
__global__ __launch_bounds__(256) void prep_kernel(
    const float* __restrict__ w1a, const float* __restrict__ w1b,
    const float* __restrict__ w2a, const float* __restrict__ w2b,
    const float* __restrict__ w3a, const float* __restrict__ wg,
    float* __restrict__ wp1A, float* __restrict__ wp1B,
    float* __restrict__ wp2A, float* __restrict__ wp2B,
    float* __restrict__ wp3A, float* __restrict__ wgT)
{
  const int t0 = blockIdx.x * blockDim.x + threadIdx.x;
  const int NT = gridDim.x * blockDim.x;
  for (int f = t0; f < 512; f += NT) {            // wp1A [2][64] f4, folded
    int i = f & 3, o = (f >> 2) & 63, c4 = f >> 8, c = c4 * 4 + i;
    float v = 0.f;
    if (c < 3)      v = w1a[o*12 + c]     + w1a[o*12 + c + 3];
    else if (c < 6) v = w1a[o*12 + c + 3] + w1a[o*12 + c + 6];
    wp1A[f] = v;
  }
  for (int f = t0; f < 4096; f += NT) {           // wp1B / wp2B [16][64] f4
    int i = f & 3, o = (f >> 2) & 63, c4 = f >> 8, c = c4 * 4 + i;
    wp1B[f] = w1b[o*64 + c];
    wp2B[f] = w2b[o*64 + c];
  }
  for (int f = t0; f < 8192; f += NT) {           // wp2A / wp3A [32][64] f4
    int i = f & 3, o = (f >> 2) & 63, c4 = f >> 8, c = c4 * 4 + i;
    wp2A[f] = w2a[o*128 + c];
    wp3A[f] = w3a[o*128 + c];
  }
  for (int f = t0; f < 192 * 1024; f += NT) {     // wgT [192][1024]
    int c = f >> 10, o = f & 1023;
    wgT[f] = wg[o*192 + c];
  }
}

// ---------------------------------------------------------------- point norms
__global__ __launch_bounds__(256) void xx_points(const float* __restrict__ pts,
                                                 float* __restrict__ xx)
{
  int t = blockIdx.x * 256 + threadIdx.x;
  if (t < 2 * NPTS) {
    const float* p = pts + (size_t)t * 3;
    xx[t] = p[0]*p[0] + p[1]*p[1] + p[2]*p[2];
  }
}

// ---------------------------------------------------------------- kNN
// 4 query rows/block (wave = row), 134KB LDS, 1 block/CU.
// Distance pass: block-cooperative (feat row j read ONCE for 4 query rows —
// 4x less L2 traffic), centers as uniform LDS broadcasts, j-pairs double-
// buffered in registers to hide L2 latency.
// Selection: per-wave hierarchical argmax, zero barriers in the 20-iter loop.
// 128 chunk-maxima per row; init scan uses diagonal rotation (conflict-free);
// phase reads are stride-1 (conflict-free). All LDS marks/repairs are written
// by EVERY lane (same addr, same value) so each lane's subsequent reads are
// ordered after its own write — no cross-lane wave-ordering assumptions.
// Ties: lower chunk, then lower j == lax.top_k order.
template<int D>
__global__ __launch_bounds__(256) void knn_kernel(
    const float* __restrict__ feat, int fstride, int foff,
    const float* __restrict__ xx, int* __restrict__ idxout)
{
  __shared__ __align__(16) float sd[4][NPTS];          // 128 KB
  __shared__ __align__(16) float s_ctr[4][(D > 4) ? D : 4];
  __shared__ float s_cmax[4][128];                     // 2 KB
  const int tid = threadIdx.x;
  const int b   = blockIdx.x / (NPTS / 4);
  const int r0  = (blockIdx.x % (NPTS / 4)) * 4;
  const size_t rowbase = (size_t)b * NPTS;

  for (int i = tid; i < 4 * D; i += 256)
    s_ctr[i / D][i % D] = feat[(rowbase + r0 + (i / D)) * fstride + foff + (i % D)];
  __syncthreads();

  const float xr0 = xx[rowbase + r0 + 0], xr1 = xx[rowbase + r0 + 1];
  const float xr2 = xx[rowbase + r0 + 2], xr3 = xx[rowbase + r0 + 3];

  if (D == 64) {
    const float4* c0 = (const float4*)s_ctr[0];
    const float4* c1 = (const float4*)s_ctr[1];
    const float4* c2 = (const float4*)s_ctr[2];
    const float4* c3 = (const float4*)s_ctr[3];
    for (int jj = 0; jj < NPTS / 256; jj += 2) {
      const int j0 = jj * 256 + tid, j1 = j0 + 256;
      const float4* fa = (const float4*)(feat + (rowbase + j0) * fstride + foff);
      const float4* fb = (const float4*)(feat + (rowbase + j1) * fstride + foff);
      float4 A[16], B[16];
      #pragma unroll
      for (int c = 0; c < 16; ++c) A[c] = fa[c];
      #pragma unroll
      for (int c = 0; c < 16; ++c) B[c] = fb[c];
      const float xa = xx[rowbase + j0], xb = xx[rowbase + j1];
      float i0 = 0.f, i1 = 0.f, i2 = 0.f, i3 = 0.f;
      #pragma unroll
      for (int c = 0; c < 16; ++c) {
        float4 f = A[c]; float4 a;
        a = c0[c]; i0 += f.x*a.x + f.y*a.y + f.z*a.z + f.w*a.w;
        a = c1[c]; i1 += f.x*a.x + f.y*a.y + f.z*a.z + f.w*a.w;
        a = c2[c]; i2 += f.x*a.x + f.y*a.y + f.z*a.z + f.w*a.w;
        a = c3[c]; i3 += f.x*a.x + f.y*a.y + f.z*a.z + f.w*a.w;
      }
      sd[0][j0] = 2.f*i0 - xr0 - xa;
      sd[1][j0] = 2.f*i1 - xr1 - xa;
      sd[2][j0] = 2.f*i2 - xr2 - xa;
      sd[3][j0] = 2.f*i3 - xr3 - xa;
      i0 = i1 = i2 = i3 = 0.f;
      #pragma unroll
      for (int c = 0; c < 16; ++c) {
        float4 f = B[c]; float4 a;
        a = c0[c]; i0 += f.x*a.x + f.y*a.y + f.z*a.z + f.w*a.w;
        a = c1[c]; i1 += f.x*a.x + f.y*a.y + f.z*a.z + f.w*a.w;
        a = c2[c]; i2 += f.x*a.x + f.y*a.y + f.z*a.z + f.w*a.w;
        a = c3[c]; i3 += f.x*a.x + f.y*a.y + f.z*a.z + f.w*a.w;
      }
      sd[0][j1] = 2.f*i0 - xr0 - xb;
      sd[1][j1] = 2.f*i1 - xr1 - xb;
      sd[2][j1] = 2.f*i2 - xr2 - xb;
      sd[3][j1] = 2.f*i3 - xr3 - xb;
    }
  } else {
    for (int j = tid; j < NPTS; j += 256) {
      const float* fj = feat + (rowbase + j) * fstride + foff;
      const float f0 = fj[0], f1 = fj[1], f2 = fj[2];
      const float xj = xx[rowbase + j];
      sd[0][j] = 2.f*(f0*s_ctr[0][0] + f1*s_ctr[0][1] + f2*s_ctr[0][2]) - xr0 - xj;
      sd[1][j] = 2.f*(f0*s_ctr[1][0] + f1*s_ctr[1][1] + f2*s_ctr[1][2]) - xr1 - xj;
      sd[2][j] = 2.f*(f0*s_ctr[2][0] + f1*s_ctr[2][1] + f2*s_ctr[2][2]) - xr2 - xj;
      sd[3][j] = 2.f*(f0*s_ctr[3][0] + f1*s_ctr[3][1] + f2*s_ctr[3][2]) - xr3 - xj;
    }
  }
  __syncthreads();

  // chunk maxima: 4 rows x 128 chunks of 64; diagonal order -> conflict-free
  for (int i = tid; i < 4 * 128; i += 256) {
    const int rr = i >> 7, c = i & 127;
    float m = -INFINITY;
    #pragma unroll
    for (int t = 0; t < 64; ++t)
      m = fmaxf(m, sd[rr][c * 64 + ((t + c) & 63)]);
    s_cmax[rr][c] = m;
  }
  __syncthreads();

  const int r = tid >> 6, lane = tid & 63;
  int* orow = idxout + (rowbase + r0 + r) * KNN;

  for (int kk = 0; kk < KNN; ++kk) {
    // phase 1: best chunk (tie -> lower chunk)
    float bv = s_cmax[r][lane]; int bc = lane;
    { float v2 = s_cmax[r][lane + 64]; if (v2 > bv) { bv = v2; bc = lane + 64; } }
    #pragma unroll
    for (int m = 32; m >= 1; m >>= 1) {
      float ov = __shfl_xor(bv, m); int oc = __shfl_xor(bc, m);
      if (ov > bv || (ov == bv && oc < bc)) { bv = ov; bc = oc; }
    }
    // phase 2: argmax within chunk (tie -> lower j); stride-1, conflict-free
    const int j = bc * 64 + lane;
    float pv = sd[r][j]; int bj = j;
    #pragma unroll
    for (int m = 32; m >= 1; m >>= 1) {
      float ov = __shfl_xor(pv, m); int oj = __shfl_xor(bj, m);
      if (ov > pv || (ov == pv && oj < bj)) { pv = ov; bj = oj; }
    }
    if (lane == 0) orow[kk] = bj;
    sd[r][bj] = -INFINITY;                 // ALL lanes: same addr, same value
    // phase 3: repair chunk max
    float nv = sd[r][bc * 64 + lane];
    #pragma unroll
    for (int m = 32; m >= 1; m >>= 1) nv = fmaxf(nv, __shfl_xor(nv, m));
    s_cmax[r][bc] = nv;                    // ALL lanes: same addr, same value
  }
}

// ---------------------------------------------------------------- fused EdgeConv
// Block = 4 points x 64 channels (wave = one point). All LDS <= 64KB (KC=4).
template<int D, bool HASB, bool WXX>
__global__ __launch_bounds__(256) void fused_conv(
    const float* __restrict__ feat, int fstride, int foff,
    const int* __restrict__ idx,
    const float4* __restrict__ wAp, const float* __restrict__ sa, const float* __restrict__ ba,
    const float4* __restrict__ wBp, const float* __restrict__ sb, const float* __restrict__ bb,
    float* __restrict__ outbuf, int ooff, float* __restrict__ xxout)
{
  constexpr int CHA  = (D == 64) ? 32 : 2;   // float4 chunks of 2D (padded)
  constexpr int CHA4 = CHA * 4;
  __shared__ float4 s_wA[CHA * 64];
  __shared__ float4 s_wB[HASB ? 16 * 64 : 1];
  __shared__ __align__(16) float4 s_g[4 * KC * CHA];
  __shared__ __align__(16) float  s_h1[HASB ? 4 * KC * 64 : 4];
  __shared__ float s_ctr[4][(D > 4) ? D : 4];
  __shared__ float s_sa[64], s_ba[64], s_sb[64], s_bb[64];

  const int tid = threadIdx.x;
  const int p = tid >> 6, o = tid & 63;
  const int b  = blockIdx.x / (NPTS / 4);
  const int p0 = (blockIdx.x % (NPTS / 4)) * 4;
  const size_t rowbase = (size_t)b * NPTS;

  for (int i = tid; i < CHA * 64; i += 256) s_wA[i] = wAp[i];
  if (HASB) for (int i = tid; i < 16 * 64; i += 256) s_wB[i] = wBp[i];
  if (tid < 64) {
    s_sa[tid] = sa[tid]; s_ba[tid] = ba[tid];
    if (HASB) { s_sb[tid] = sb[tid]; s_bb[tid] = bb[tid]; }
  }
  for (int i = tid; i < 4 * D; i += 256)
    s_ctr[i / D][i % D] = feat[(rowbase + p0 + (i / D)) * fstride + foff + (i % D)];
  __syncthreads();

  float* s_gf = (float*)s_g;
  float hmax = -INFINITY;
  for (int kc = 0; kc < KNN / KC; ++kc) {
    for (int s = tid; s < 4 * KC * CHA4; s += 256) {
      int pp = s / (KC * CHA4);
      int rr = s - pp * (KC * CHA4);
      int kk = rr / CHA4;
      int c  = rr - kk * CHA4;
      int nb = idx[(rowbase + p0 + pp) * KNN + kc * KC + kk];
      float v;
      if (D == 64) {
        v = (c < 64) ? (feat[(rowbase + nb) * fstride + foff + c] - s_ctr[pp][c])
                     : s_ctr[pp][c - 64];
      } else {
        if (c < 3)      v = feat[(rowbase + nb) * 3 + c] - s_ctr[pp][c];
        else if (c < 6) v = s_ctr[pp][c - 3];
        else            v = 0.f;
      }
      s_gf[s] = v;
    }
    __syncthreads();

    float acc[KC];
    #pragma unroll
    for (int kk = 0; kk < KC; ++kk) acc[kk] = 0.f;
    for (int c4 = 0; c4 < CHA; ++c4) {
      float4 w = s_wA[c4 * 64 + o];
      #pragma unroll
      for (int kk = 0; kk < KC; ++kk) {
        float4 g = s_g[(p * KC + kk) * CHA + c4];
        acc[kk] += w.x*g.x + w.y*g.y + w.z*g.z + w.w*g.w;
      }
    }
    if (HASB) {
      #pragma unroll
      for (int kk = 0; kk < KC; ++kk)
        s_h1[(p * KC + kk) * 64 + o] = lrelu(acc[kk] * s_sa[o] + s_ba[o]);
      __syncthreads();
      float acc2[KC];
      #pragma unroll
      for (int kk = 0; kk < KC; ++kk) acc2[kk] = 0.f;
      const float4* s_h14 = (const float4*)s_h1;
      for (int c4 = 0; c4 < 16; ++c4) {
        float4 w = s_wB[c4 * 64 + o];
        #pragma unroll
        for (int kk = 0; kk < KC; ++kk) {
          float4 h = s_h14[(p * KC + kk) * 16 + c4];
          acc2[kk] += w.x*h.x + w.y*h.y + w.z*h.z + w.w*h.w;
        }
      }
      #pragma unroll
      for (int kk = 0; kk < KC; ++kk)
        hmax = fmaxf(hmax, lrelu(acc2[kk] * s_sb[o] + s_bb[o]));
      __syncthreads();
    } else {
      #pragma unroll
      for (int kk = 0; kk < KC; ++kk)
        hmax = fmaxf(hmax, lrelu(acc[kk] * s_sa[o] + s_ba[o]));
      __syncthreads();
    }
  }
  outbuf[(rowbase + p0 + p) * 192 + ooff + o] = hmax;
  if (WXX) {
    float ss = hmax * hmax;
    #pragma unroll
    for (int m = 1; m < 64; m <<= 1) ss += __shfl_xor(ss, m);
    if (o == 0) xxout[rowbase + p0 + p] = ss;
  }
}

// ---------------------------------------------------------------- final 192->1024
__global__ __launch_bounds__(256) void init_gmax(unsigned* __restrict__ g)
{
  int t = blockIdx.x * 256 + threadIdx.x;
  if (t < 2048) g[t] = fkey(-1e30f);
}

__global__ __launch_bounds__(256) void final_kernel(
    const float* __restrict__ cat, const float* __restrict__ wgT,
    const float* __restrict__ sg, const float* __restrict__ bg,
    unsigned* __restrict__ gmax)
{
  const int tid = threadIdx.x;
  const int chunk = blockIdx.x & 15;
  const int grp   = blockIdx.x >> 4;
  const int pt = grp * 256 + tid;
  const int b  = pt >> 13;
  const float4* crow = (const float4*)(cat + (size_t)pt * 192);
  float acc[64];
  #pragma unroll
  for (int o = 0; o < 64; ++o) acc[o] = 0.f;
  for (int c4 = 0; c4 < 48; ++c4) {
    float4 cv = crow[c4];
    const float* w0 = wgT + (size_t)(c4 * 4) * 1024 + chunk * 64;
    const float* w1 = w0 + 1024;
    const float* w2 = w1 + 1024;
    const float* w3 = w2 + 1024;
    #pragma unroll
    for (int o = 0; o < 64; ++o)
      acc[o] += cv.x*w0[o] + cv.y*w1[o] + cv.z*w2[o] + cv.w*w3[o];
  }
  const int lane = tid & 63;
  #pragma unroll
  for (int o = 0; o < 64; ++o) {
    int ch = chunk * 64 + o;
    float h = lrelu(acc[o] * sg[ch] + bg[ch]);
    #pragma unroll
    for (int m = 1; m < 64; m <<= 1) h = fmaxf(h, __shfl_xor(h, m));
    if (lane == 0) atomicMax(&gmax[b * 1024 + ch], fkey(h));
  }
}

// Output is FP32: [2][1024][8192] floats.
__global__ __launch_bounds__(256) void bcast_kernel(const unsigned* __restrict__ gmax,
                                                    float* __restrict__ out)
{
  int t = blockIdx.x * 256 + threadIdx.x;   // each thread: 4 floats = 16B
  int bo = t >> 11;
  float v = funkey(gmax[bo]);
  float4 w; w.x = v; w.y = v; w.z = v; w.w = v;
  ((float4*)out)[t] = w;
}

// ---------------------------------------------------------------- launch
extern "C" void kernel_launch(void* const* d_in, const int* in_sizes, int n_in,
                              void* d_out, int out_size, void* d_ws, size_t ws_size,
                              hipStream_t stream)
{
  const float* points = (const float*)d_in[0];
  const float* w1a = (const float*)d_in[1];  const float* s1a = (const float*)d_in[2];  const float* b1a = (const float*)d_in[3];
  const float* w1b = (const float*)d_in[4];  const float* s1b = (const float*)d_in[5];  const float* b1b = (const float*)d_in[6];
  const float* w2a = (const float*)d_in[7];  const float* s2a = (const float*)d_in[8];  const float* b2a = (const float*)d_in[9];
  const float* w2b = (const float*)d_in[10]; const float* s2b = (const float*)d_in[11]; const float* b2b = (const float*)d_in[12];
  const float* w3a = (const float*)d_in[13]; const float* s3a = (const float*)d_in[14]; const float* b3a = (const float*)d_in[15];
  const float* wg  = (const float*)d_in[16]; const float* sg  = (const float*)d_in[17]; const float* bg  = (const float*)d_in[18];

  char* ws = (char*)d_ws;
  float*    cat   = (float*)(ws);                   // [2*8192][192]  12,582,912 B
  float*    xxbuf = (float*)(ws + 12582912);        // [2*8192]           65,536 B
  int*      idxb  = (int*)  (ws + 12648448);        // [2*8192][20]    1,310,720 B
  float*    wp1A  = (float*)(ws + 13959168);
  float*    wp1B  = (float*)(ws + 13961216);
  float*    wp2A  = (float*)(ws + 13977600);
  float*    wp2B  = (float*)(ws + 14010368);
  float*    wp3A  = (float*)(ws + 14026752);
  float*    wgT   = (float*)(ws + 14059520);
  unsigned* gmax  = (unsigned*)(ws + 14845952);
  const size_t WS_NEED = 14854144;
  if (ws_size < WS_NEED || n_in != 19) return;

  prep_kernel<<<256, 256, 0, stream>>>(w1a, w1b, w2a, w2b, w3a, wg,
                                       wp1A, wp1B, wp2A, wp2B, wp3A, wgT);
  xx_points<<<64, 256, 0, stream>>>(points, xxbuf);
  knn_kernel<3><<<4096, 256, 0, stream>>>(points, 3, 0, xxbuf, idxb);
  fused_conv<3, true, true><<<4096, 256, 0, stream>>>(
      points, 3, 0, idxb, (const float4*)wp1A, s1a, b1a,
      (const float4*)wp1B, s1b, b1b, cat, 0, xxbuf);
  knn_kernel<64><<<4096, 256, 0, stream>>>(cat, 192, 0, xxbuf, idxb);
  fused_conv<64, true, true><<<4096, 256, 0, stream>>>(
      cat, 192, 0, idxb, (const float4*)wp2A, s2a, b2a,
      (const float4*)wp2B, s2b, b2b, cat, 64, xxbuf);
  knn_kernel<64><<<4096, 256, 0, stream>>>(cat, 192, 64, xxbuf, idxb);
  fused_conv<64, false, false><<<4096, 256, 0, stream>>>(
      cat, 192, 64, idxb, (const float4*)wp3A, s3a, b3a,
      nullptr, nullptr, nullptr, cat, 128, nullptr);
  init_gmax<<<8, 256, 0, stream>>>(gmax);
  final_kernel<<<1024, 256, 0, stream>>>(cat, wgT, sg, bg, gmax);
  bcast_kernel<<<16384, 256, 0, stream>>>(gmax, (float*)d_out);
}